// Round 5
// baseline (79.000 us; speedup 1.0000x reference)
//
#include <hip/hip_runtime.h>
#include <hip/hip_cooperative_groups.h>
#include <math.h>

namespace cg = cooperative_groups;

#define HI 128
#define WI 128
#define BB 2
#define PG 1024
#define NE (BB*PG)

#define OFF_ALPHA (BB*3*HI*WI)            /* 98304  */
#define OFF_ESTC  (OFF_ALPHA + BB*HI*WI)  /* 131072 */
#define OFF_ESTW  (OFF_ESTC + BB*PG*3)    /* 137216 */
#define OFF_RADII (OFF_ESTW + BB*PG)      /* 139264 */

// ws: preA[NE](px,py,A,B) preB[NE](C,pmin,op,0) preC[NE](cR,cG,cB,0)
//     cull[NE](px,py,ex,ey) keys[NE] u32 sortable-depth

__global__ __launch_bounds__(64) void fused_kernel(
    const float* __restrict__ means, const float* __restrict__ sh,
    const float* __restrict__ opac, const float* __restrict__ scales,
    const float* __restrict__ rots, const float* __restrict__ vm,
    const float* __restrict__ pm, const float* __restrict__ campos,
    float4* __restrict__ preA, float4* __restrict__ preB,
    float4* __restrict__ preC, float4* __restrict__ cullv,
    unsigned int* __restrict__ keys,
    const float* __restrict__ target, const float* __restrict__ bg,
    float* __restrict__ out)
{
  const int t = threadIdx.x;
  const int flatb = (blockIdx.z * gridDim.y + blockIdx.y) * gridDim.x + blockIdx.x;
  const int gid = flatb * 64 + t;

  // ================= phase 1: preprocess (first NE threads) =================
  if (gid < NE) {
    ((float4*)(out + OFF_ESTC))[gid] = make_float4(0.f, 0.f, 0.f, 0.f);

    float mx = means[gid*3+0], my = means[gid*3+1], mz = means[gid*3+2];

    float hom0 = pm[0]*mx + pm[1]*my + pm[2]*mz + pm[3];
    float hom1 = pm[4]*mx + pm[5]*my + pm[6]*mz + pm[7];
    float hom3 = pm[12]*mx + pm[13]*my + pm[14]*mz + pm[15];
    float p_w  = 1.0f / (hom3 + 1e-7f);
    float pp0 = hom0 * p_w, pp1 = hom1 * p_w;

    float pv0   = vm[0]*mx + vm[1]*my + vm[2]*mz  + vm[3];
    float pv1   = vm[4]*mx + vm[5]*my + vm[6]*mz  + vm[7];
    float depth = vm[8]*mx + vm[9]*my + vm[10]*mz + vm[11];

    float qr = rots[gid*4+0], qx = rots[gid*4+1], qy = rots[gid*4+2], qz = rots[gid*4+3];
    float qn = sqrtf(qr*qr + qx*qx + qy*qy + qz*qz);
    qr /= qn; qx /= qn; qy /= qn; qz /= qn;
    float R00 = 1.0f-2.0f*(qy*qy+qz*qz), R01 = 2.0f*(qx*qy-qr*qz), R02 = 2.0f*(qx*qz+qr*qy);
    float R10 = 2.0f*(qx*qy+qr*qz), R11 = 1.0f-2.0f*(qx*qx+qz*qz), R12 = 2.0f*(qy*qz-qr*qx);
    float R20 = 2.0f*(qx*qz-qr*qy), R21 = 2.0f*(qy*qz+qr*qx), R22 = 1.0f-2.0f*(qx*qx+qy*qy);

    float s0 = scales[gid*3+0], s1 = scales[gid*3+1], s2 = scales[gid*3+2];
    float M00=R00*s0, M01=R01*s1, M02=R02*s2;
    float M10=R10*s0, M11=R11*s1, M12=R12*s2;
    float M20=R20*s0, M21=R21*s1, M22=R22*s2;
    float S00 = M00*M00+M01*M01+M02*M02;
    float S01 = M00*M10+M01*M11+M02*M12;
    float S02 = M00*M20+M01*M21+M02*M22;
    float S11 = M10*M10+M11*M11+M12*M12;
    float S12 = M10*M20+M11*M21+M12*M22;
    float S22 = M20*M20+M21*M21+M22*M22;

    const float fx = 128.0f, fyc = 128.0f;
    float tz = depth;
    float txc = fminf(fmaxf(pv0/tz, -0.65f), 0.65f) * tz;
    float tyc = fminf(fmaxf(pv1/tz, -0.65f), 0.65f) * tz;
    float J00 = fx/tz,  J02 = -fx*txc/(tz*tz);
    float J11 = fyc/tz, J12 = -fyc*tyc/(tz*tz);

    float T00 = J00*vm[0] + J02*vm[8];
    float T01 = J00*vm[1] + J02*vm[9];
    float T02 = J00*vm[2] + J02*vm[10];
    float T10 = J11*vm[4] + J12*vm[8];
    float T11 = J11*vm[5] + J12*vm[9];
    float T12 = J11*vm[6] + J12*vm[10];

    float TS00 = T00*S00 + T01*S01 + T02*S02;
    float TS01 = T00*S01 + T01*S11 + T02*S12;
    float TS02 = T00*S02 + T01*S12 + T02*S22;
    float TS10 = T10*S00 + T11*S01 + T12*S02;
    float TS11 = T10*S01 + T11*S11 + T12*S12;
    float TS12 = T10*S02 + T11*S12 + T12*S22;

    float c00 = TS00*T00 + TS01*T01 + TS02*T02 + 0.3f;
    float c01 = TS00*T10 + TS01*T11 + TS02*T12;
    float c11 = TS10*T10 + TS11*T11 + TS12*T12 + 0.3f;

    float det = c00*c11 - c01*c01;
    bool valid = (depth > 0.2f) && (det > 1e-12f);
    float inv_det = 1.0f / (det > 1e-12f ? det : 1.0f);
    float A  =  c11 * inv_det;
    float Bc = -c01 * inv_det;
    float Cc =  c00 * inv_det;
    float mid = 0.5f * (c00 + c11);
    float lam = mid + sqrtf(fmaxf(mid*mid - det, 0.1f));
    float radii = valid ? ceilf(3.0f * sqrtf(lam)) : 0.0f;

    float px = ((pp0 + 1.0f)*WI - 1.0f)*0.5f;
    float py = ((pp1 + 1.0f)*HI - 1.0f)*0.5f;

    // SH degree 3
    float dxr = mx - campos[0], dyr = my - campos[1], dzr = mz - campos[2];
    float dn = sqrtf(dxr*dxr + dyr*dyr + dzr*dzr);
    float x = dxr/dn, y = dyr/dn, z = dzr/dn;
    float xx=x*x, yy=y*y, zz=z*z, xy=x*y, yz=y*z, xz=x*z;
    const float* S = sh + gid*48;
    float col[3];
    #pragma unroll
    for (int c = 0; c < 3; ++c) {
      float r = 0.28209479177387814f * S[0+c];
      r -= 0.4886025119029199f * y * S[3+c];
      r += 0.4886025119029199f * z * S[6+c];
      r -= 0.4886025119029199f * x * S[9+c];
      r += 1.0925484305920792f  * xy * S[12+c];
      r += -1.0925484305920792f * yz * S[15+c];
      r += 0.31539156525252005f * (2.0f*zz-xx-yy) * S[18+c];
      r += -1.0925484305920792f * xz * S[21+c];
      r += 0.5462742152960396f  * (xx-yy) * S[24+c];
      r += -0.5900435899266435f * y * (3.0f*xx-yy) * S[27+c];
      r += 2.890611442640554f   * xy * z * S[30+c];
      r += -0.4570457994644658f * y * (4.0f*zz-xx-yy) * S[33+c];
      r += 0.3731763325901154f  * z * (2.0f*zz-3.0f*xx-3.0f*yy) * S[36+c];
      r += -0.4570457994644658f * x * (4.0f*zz-xx-yy) * S[39+c];
      r += 1.445305721320277f   * z * (xx-yy) * S[42+c];
      r += -0.5900435899266435f * x * (xx-3.0f*yy) * S[45+c];
      col[c] = fmaxf(r + 0.5f, 0.0f);
    }

    float op = opac[gid];
    float tau = logf(255.0f * op);
    bool rok = valid && (tau > 0.0f);
    float ex = rok ? sqrtf(2.0f*tau*c00) + 0.02f : -1e9f;
    float ey = rok ? sqrtf(2.0f*tau*c11) + 0.02f : -1e9f;

    preA[gid] = make_float4(px, py, A, Bc);
    preB[gid] = make_float4(Cc, -tau, op, 0.0f);
    preC[gid] = make_float4(col[0], col[1], col[2], 0.0f);
    cullv[gid] = make_float4(px, py, ex, ey);

    unsigned int u = __float_as_uint(depth);
    keys[gid] = (u >> 31) ? ~u : (u | 0x80000000u);
    out[OFF_RADII + gid] = radii;
  }

  cg::this_grid().sync();

  // ================= phase 2: per-tile render =================
  const int b = blockIdx.z;
  const int x = blockIdx.x*8 + (t & 7);
  const int y = blockIdx.y*8 + (t >> 3);
  const float fxp = (float)x, fyp = (float)y;
  const float tx0 = (float)(blockIdx.x*8), ty0 = (float)(blockIdx.y*8);

  __shared__ unsigned long long skey[PG];
  __shared__ float4 sqA[64], sqB[64], sqC[64];
  __shared__ float4 stgt[64];
  __shared__ float  wmat[64][65];

  const float4* csrc = cullv + (b << 10);
  const unsigned int* kb = keys + (b << 10);

  int total = 0;
  #pragma unroll
  for (int c0 = 0; c0 < PG; c0 += 64) {
    float4 cv = csrc[c0 + t];
    unsigned int kk = kb[c0 + t];
    bool ok = (cv.x + cv.z >= tx0) && (cv.x - cv.z <= tx0 + 7.0f)
           && (cv.y + cv.w >= ty0) && (cv.y - cv.w <= ty0 + 7.0f);
    unsigned long long m = __ballot(ok);
    if (ok) {
      int pos = total + __popcll(m & ((1ull << t) - 1ull));
      skey[pos] = (((unsigned long long)kk) << 10) | (unsigned)(c0 + t);
    }
    total += __popcll(m);
  }
  __syncthreads();

  if (total > 1) {
    if (total <= 64) {
      unsigned long long v = (t < total) ? skey[t] : ~0ull;
      #pragma unroll
      for (int k = 2; k <= 64; k <<= 1) {
        bool dirAsc = ((t & k) == 0);
        #pragma unroll
        for (int j = k >> 1; j > 0; j >>= 1) {
          unsigned long long o = __shfl_xor(v, j, 64);
          bool takeMin = (((t & j) == 0) == dirAsc);
          bool less = v < o;
          v = (takeMin == less) ? v : o;
        }
      }
      if (t < total) skey[t] = v;
    } else {
      int M = 64; while (M < total) M <<= 1;
      for (int s = total + t; s < M; s += 64) skey[s] = ~0ull;
      __syncthreads();
      for (int k = 2; k <= M; k <<= 1) {
        for (int j = k >> 1; j > 0; j >>= 1) {
          for (int base = t; base < M; base += 64) {
            int ixj = base ^ j;
            if (ixj > base) {
              unsigned long long a = skey[base], bq = skey[ixj];
              bool up = ((base & k) == 0);
              if ((a > bq) == up) { skey[base] = bq; skey[ixj] = a; }
            }
          }
          __syncthreads();
        }
      }
    }
  }

  const float t0 = target[((b*3+0)*HI + y)*WI + x];
  const float t1 = target[((b*3+1)*HI + y)*WI + x];
  const float t2 = target[((b*3+2)*HI + y)*WI + x];
  stgt[t] = make_float4(t0, t1, t2, 1.0f);
  __syncthreads();

  float* est_col = out + OFF_ESTC + b*PG*3;
  float* est_w   = out + OFF_ESTW + b*PG;

  float T = 1.0f, a0 = 0.0f, a1 = 0.0f, a2 = 0.0f;

  for (int c = 0; c < total; c += 64) {
    int count = min(64, total - c);
    if (t < count) {
      int g = (int)(skey[c + t] & 1023u);
      int e = (b << 10) + g;
      float4 qb = preB[e];
      qb.w = __int_as_float(g);
      sqA[t] = preA[e]; sqB[t] = qb; sqC[t] = preC[e];
    }
    __syncthreads();

    for (int i = 0; i < count; ++i) {
      float4 q0 = sqA[i], q1 = sqB[i], q2 = sqC[i];
      float dx = q0.x - fxp, dy = q0.y - fyp;
      float power = -0.5f*(q0.z*dx*dx + q1.x*dy*dy) - q0.w*dx*dy;
      float alpha = fminf(0.99f, q1.z * __expf(power));
      bool keep = (power <= 0.0f) && (alpha >= (1.0f/255.0f));
      float w = keep ? alpha * T : 0.0f;
      a0 += w * q2.x; a1 += w * q2.y; a2 += w * q2.z;
      T -= w;
      wmat[i][t] = w;
    }
    __syncthreads();

    if (t < count) {
      float4 acc = make_float4(0.f, 0.f, 0.f, 0.f);
      #pragma unroll 8
      for (int p = 0; p < 64; ++p) {
        float w = wmat[t][p];
        float4 tg = stgt[p];
        acc.x += w * tg.x; acc.y += w * tg.y; acc.z += w * tg.z; acc.w += w;
      }
      int orig = __float_as_int(sqB[t].w);
      atomicAdd(&est_col[orig*3+0], acc.x);
      atomicAdd(&est_col[orig*3+1], acc.y);
      atomicAdd(&est_col[orig*3+2], acc.z);
      atomicAdd(&est_w[orig], acc.w);
    }
    __syncthreads();
  }

  out[((b*3+0)*HI + y)*WI + x] = a0 + T * bg[b*3+0];
  out[((b*3+1)*HI + y)*WI + x] = a1 + T * bg[b*3+1];
  out[((b*3+2)*HI + y)*WI + x] = a2 + T * bg[b*3+2];
  out[OFF_ALPHA + (b*HI + y)*WI + x] = 1.0f - T;
}

extern "C" void kernel_launch(void* const* d_in, const int* in_sizes, int n_in,
                              void* d_out, int out_size, void* d_ws, size_t ws_size,
                              hipStream_t stream) {
  const float* means  = (const float*)d_in[0];
  const float* sh     = (const float*)d_in[1];
  const float* opac   = (const float*)d_in[2];
  const float* scales = (const float*)d_in[3];
  const float* rots   = (const float*)d_in[4];
  const float* target = (const float*)d_in[5];
  const float* bg     = (const float*)d_in[6];
  const float* vm     = (const float*)d_in[7];
  const float* pm     = (const float*)d_in[8];
  const float* campos = (const float*)d_in[9];
  float* out = (float*)d_out;

  float4* preA = (float4*)d_ws;
  float4* preB = preA + NE;
  float4* preC = preB + NE;
  float4* cul  = preC + NE;
  unsigned int* keys = (unsigned int*)(cul + NE);

  void* args[] = {
    (void*)&means, (void*)&sh, (void*)&opac, (void*)&scales, (void*)&rots,
    (void*)&vm, (void*)&pm, (void*)&campos,
    (void*)&preA, (void*)&preB, (void*)&preC, (void*)&cul, (void*)&keys,
    (void*)&target, (void*)&bg, (void*)&out
  };
  hipLaunchCooperativeKernel((const void*)fused_kernel,
                             dim3(WI/8, HI/8, BB), dim3(64, 1, 1),
                             args, 0, stream);
}

// Round 6
// 42.357 us; speedup vs baseline: 1.8651x; 1.8651x over previous
//
#include <hip/hip_runtime.h>
#include <math.h>

#define HI 128
#define WI 128
#define BB 2
#define PG 1024
#define NE (BB*PG)

#define OFF_ALPHA (BB*3*HI*WI)            /* 98304  */
#define OFF_ESTC  (OFF_ALPHA + BB*HI*WI)  /* 131072 */
#define OFF_ESTW  (OFF_ESTC + BB*PG*3)    /* 137216 */
#define OFF_RADII (OFF_ESTW + BB*PG)      /* 139264 */

struct PC {
  float px, py, ex, ey;     // screen center + bbox half-extents (alpha>=1/255 superset)
  float A, B, C, op;        // conic + opacity
  unsigned key;             // sortable depth bits
  float radii;
};

__device__ __forceinline__ PC proj_cull(int e,
    const float* __restrict__ means, const float* __restrict__ opac,
    const float* __restrict__ scales, const float* __restrict__ rots,
    const float* __restrict__ vm, const float* __restrict__ pm)
{
  PC o;
  float mx = means[e*3+0], my = means[e*3+1], mz = means[e*3+2];

  float hom0 = pm[0]*mx + pm[1]*my + pm[2]*mz + pm[3];
  float hom1 = pm[4]*mx + pm[5]*my + pm[6]*mz + pm[7];
  float hom3 = pm[12]*mx + pm[13]*my + pm[14]*mz + pm[15];
  float p_w  = 1.0f / (hom3 + 1e-7f);
  float pp0 = hom0 * p_w, pp1 = hom1 * p_w;

  float pv0   = vm[0]*mx + vm[1]*my + vm[2]*mz  + vm[3];
  float pv1   = vm[4]*mx + vm[5]*my + vm[6]*mz  + vm[7];
  float depth = vm[8]*mx + vm[9]*my + vm[10]*mz + vm[11];

  float qr = rots[e*4+0], qx = rots[e*4+1], qy = rots[e*4+2], qz = rots[e*4+3];
  float qn = sqrtf(qr*qr + qx*qx + qy*qy + qz*qz);
  qr /= qn; qx /= qn; qy /= qn; qz /= qn;
  float R00 = 1.0f-2.0f*(qy*qy+qz*qz), R01 = 2.0f*(qx*qy-qr*qz), R02 = 2.0f*(qx*qz+qr*qy);
  float R10 = 2.0f*(qx*qy+qr*qz), R11 = 1.0f-2.0f*(qx*qx+qz*qz), R12 = 2.0f*(qy*qz-qr*qx);
  float R20 = 2.0f*(qx*qz-qr*qy), R21 = 2.0f*(qy*qz+qr*qx), R22 = 1.0f-2.0f*(qx*qx+qy*qy);

  float s0 = scales[e*3+0], s1 = scales[e*3+1], s2 = scales[e*3+2];
  float M00=R00*s0, M01=R01*s1, M02=R02*s2;
  float M10=R10*s0, M11=R11*s1, M12=R12*s2;
  float M20=R20*s0, M21=R21*s1, M22=R22*s2;
  float S00 = M00*M00+M01*M01+M02*M02;
  float S01 = M00*M10+M01*M11+M02*M12;
  float S02 = M00*M20+M01*M21+M02*M22;
  float S11 = M10*M10+M11*M11+M12*M12;
  float S12 = M10*M20+M11*M21+M12*M22;
  float S22 = M20*M20+M21*M21+M22*M22;

  const float fx = 128.0f, fyc = 128.0f;
  float tz = depth;
  float txc = fminf(fmaxf(pv0/tz, -0.65f), 0.65f) * tz;
  float tyc = fminf(fmaxf(pv1/tz, -0.65f), 0.65f) * tz;
  float J00 = fx/tz,  J02 = -fx*txc/(tz*tz);
  float J11 = fyc/tz, J12 = -fyc*tyc/(tz*tz);

  float T00 = J00*vm[0] + J02*vm[8];
  float T01 = J00*vm[1] + J02*vm[9];
  float T02 = J00*vm[2] + J02*vm[10];
  float T10 = J11*vm[4] + J12*vm[8];
  float T11 = J11*vm[5] + J12*vm[9];
  float T12 = J11*vm[6] + J12*vm[10];

  float TS00 = T00*S00 + T01*S01 + T02*S02;
  float TS01 = T00*S01 + T01*S11 + T02*S12;
  float TS02 = T00*S02 + T01*S12 + T02*S22;
  float TS10 = T10*S00 + T11*S01 + T12*S02;
  float TS11 = T10*S01 + T11*S11 + T12*S12;
  float TS12 = T10*S02 + T11*S12 + T12*S22;

  float c00 = TS00*T00 + TS01*T01 + TS02*T02 + 0.3f;
  float c01 = TS00*T10 + TS01*T11 + TS02*T12;
  float c11 = TS10*T10 + TS11*T11 + TS12*T12 + 0.3f;

  float det = c00*c11 - c01*c01;
  bool valid = (depth > 0.2f) && (det > 1e-12f);
  float inv_det = 1.0f / (det > 1e-12f ? det : 1.0f);
  o.A =  c11 * inv_det;
  o.B = -c01 * inv_det;
  o.C =  c00 * inv_det;
  float mid = 0.5f * (c00 + c11);
  float lam = mid + sqrtf(fmaxf(mid*mid - det, 0.1f));
  o.radii = valid ? ceilf(3.0f * sqrtf(lam)) : 0.0f;

  o.px = ((pp0 + 1.0f)*WI - 1.0f)*0.5f;
  o.py = ((pp1 + 1.0f)*HI - 1.0f)*0.5f;

  float opv = opac[e];
  o.op = opv;
  float tau = logf(255.0f * opv);
  bool rok = valid && (tau > 0.0f);
  o.ex = rok ? sqrtf(2.0f*tau*c00) + 0.02f : -1e9f;
  o.ey = rok ? sqrtf(2.0f*tau*c11) + 0.02f : -1e9f;

  unsigned u = __float_as_uint(depth);
  o.key = (u >> 31) ? ~u : (u | 0x80000000u);
  return o;
}

__device__ __forceinline__ void sh_color(int e,
    const float* __restrict__ sh, const float* __restrict__ means,
    const float* __restrict__ campos, float col[3])
{
  float mx = means[e*3+0], my = means[e*3+1], mz = means[e*3+2];
  float dxr = mx - campos[0], dyr = my - campos[1], dzr = mz - campos[2];
  float dn = sqrtf(dxr*dxr + dyr*dyr + dzr*dzr);
  float x = dxr/dn, y = dyr/dn, z = dzr/dn;
  float xx=x*x, yy=y*y, zz=z*z, xy=x*y, yz=y*z, xz=x*z;
  const float* S = sh + e*48;
  #pragma unroll
  for (int c = 0; c < 3; ++c) {
    float r = 0.28209479177387814f * S[0+c];
    r -= 0.4886025119029199f * y * S[3+c];
    r += 0.4886025119029199f * z * S[6+c];
    r -= 0.4886025119029199f * x * S[9+c];
    r += 1.0925484305920792f  * xy * S[12+c];
    r += -1.0925484305920792f * yz * S[15+c];
    r += 0.31539156525252005f * (2.0f*zz-xx-yy) * S[18+c];
    r += -1.0925484305920792f * xz * S[21+c];
    r += 0.5462742152960396f  * (xx-yy) * S[24+c];
    r += -0.5900435899266435f * y * (3.0f*xx-yy) * S[27+c];
    r += 2.890611442640554f   * xy * z * S[30+c];
    r += -0.4570457994644658f * y * (4.0f*zz-xx-yy) * S[33+c];
    r += 0.3731763325901154f  * z * (2.0f*zz-3.0f*xx-3.0f*yy) * S[36+c];
    r += -0.4570457994644658f * x * (4.0f*zz-xx-yy) * S[39+c];
    r += 1.445305721320277f   * z * (xx-yy) * S[42+c];
    r += -0.5900435899266435f * x * (xx-3.0f*yy) * S[45+c];
    col[c] = fmaxf(r + 0.5f, 0.0f);
  }
}

__device__ __forceinline__ void block_sort(unsigned long long* skey, int S,
                                           int t, int wv, int ln)
{
  if (S > 1) {
    if (S <= 64) {
      if (wv == 0) {
        unsigned long long v = (ln < S) ? skey[ln] : ~0ull;
        #pragma unroll
        for (int k = 2; k <= 64; k <<= 1) {
          bool dirAsc = ((ln & k) == 0);
          #pragma unroll
          for (int j = k >> 1; j > 0; j >>= 1) {
            unsigned long long o = __shfl_xor(v, j, 64);
            bool takeMin = (((ln & j) == 0) == dirAsc);
            bool less = v < o;
            v = (takeMin == less) ? v : o;
          }
        }
        if (ln < S) skey[ln] = v;
      }
      __syncthreads();
    } else {
      int M = 64; while (M < S) M <<= 1;
      for (int i = S + t; i < M; i += 256) skey[i] = ~0ull;
      __syncthreads();
      for (int k = 2; k <= M; k <<= 1)
        for (int j = k >> 1; j > 0; j >>= 1) {
          for (int base = t; base < M; base += 256) {
            int ixj = base ^ j;
            if (ixj > base) {
              unsigned long long a = skey[base], q = skey[ixj];
              bool up = ((base & k) == 0);
              if ((a > q) == up) { skey[base] = q; skey[ixj] = a; }
            }
          }
          __syncthreads();
        }
    }
  } else {
    __syncthreads();
  }
}

__global__ __launch_bounds__(256, 2) void fused_kernel(
    const float* __restrict__ means, const float* __restrict__ sh,
    const float* __restrict__ opac, const float* __restrict__ scales,
    const float* __restrict__ rots, const float* __restrict__ vm,
    const float* __restrict__ pm, const float* __restrict__ campos,
    const float* __restrict__ target, const float* __restrict__ bg,
    float* __restrict__ out)
{
  const int t = threadIdx.x;
  const int wv = t >> 6, ln = t & 63;
  const int blk = blockIdx.x;

  __shared__ unsigned long long skey[PG];
  __shared__ float4 recA[512], recB[512], colC[512];
  __shared__ int wcount[4];
  __shared__ float4 redbuf[4];

  if (blk < NE) {
    // ================= gaussian block: est_color / est_weight / radii =======
    const int b = blk >> 10, gi = blk & 1023;
    PC g = proj_cull(blk, means, opac, scales, rots, vm, pm);
    if (t == 0) out[OFF_RADII + blk] = g.radii;
    const unsigned long long kg = (((unsigned long long)g.key) << 10) | (unsigned)gi;

    float xs = fmaxf(ceilf(g.px - g.ex), 0.0f);
    float xe = fminf(floorf(g.px + g.ex), (float)(WI-1));
    float ys = fmaxf(ceilf(g.py - g.ey), 0.0f);
    float ye = fminf(floorf(g.py + g.ey), (float)(HI-1));
    bool anyp = (xs <= xe) && (ys <= ye);
    if (!anyp) {
      if (t == 0) {
        out[OFF_ESTC + (b*PG + gi)*3 + 0] = 0.0f;
        out[OFF_ESTC + (b*PG + gi)*3 + 1] = 0.0f;
        out[OFF_ESTC + (b*PG + gi)*3 + 2] = 0.0f;
        out[OFF_ESTW + b*PG + gi] = 0.0f;
      }
      return;
    }
    int x0=(int)xs, x1=(int)xe, y0=(int)ys, y1=(int)ye;
    int rw = x1-x0+1, npx = rw*(y1-y0+1);

    // scan: predecessors (key64 < kg) whose bbox overlaps our pixel rect
    int cnt = 0;
    for (int k = 0; k < 4; ++k) {
      int ci = wv*256 + k*64 + ln;
      PC r = proj_cull((b<<10)+ci, means, opac, scales, rots, vm, pm);
      unsigned long long k64 = (((unsigned long long)r.key) << 10) | (unsigned)ci;
      bool ok = (k64 < kg) && (r.px + r.ex >= xs) && (r.px - r.ex <= xe)
                           && (r.py + r.ey >= ys) && (r.py - r.ey <= ye);
      unsigned long long m = __ballot(ok);
      if (ok) skey[wv*256 + cnt + __popcll(m & ((1ull<<ln)-1ull))] = k64;
      cnt += __popcll(m);
    }
    if (ln == 0) wcount[wv] = cnt;
    __syncthreads();
    int c0_=wcount[0], c1_=wcount[1], c2_=wcount[2], c3_=wcount[3];
    int S = c0_+c1_+c2_+c3_;
    int off = (wv>0?c0_:0)+(wv>1?c1_:0)+(wv>2?c2_:0);
    for (int i = ln; i < cnt; i += 64) {
      unsigned long long v = skey[wv*256 + i];
      skey[off + i] = v;       // dest <= source per-wave; safe (lockstep read-then-write)
    }
    __syncthreads();
    block_sort(skey, S, t, wv, ln);

    bool small = (S <= 512);
    if (small) {
      for (int j = t; j < S; j += 256) {
        int ci = (int)(skey[j] & 1023u);
        PC r = proj_cull((b<<10)+ci, means, opac, scales, rots, vm, pm);
        recA[j] = make_float4(r.px, r.py, r.A, r.B);
        recB[j] = make_float4(r.C, r.op, 0.f, 0.f);
      }
    }
    __syncthreads();

    float ec0=0.f, ec1=0.f, ec2=0.f, ew=0.f;
    for (int p0 = 0; p0 < npx; p0 += 256) {
      int p = p0 + t;
      bool in = p < npx;
      int pi = in ? p : 0;
      int xi = x0 + (pi % rw), yi = y0 + (pi / rw);
      float fxp = (float)xi, fyp = (float)yi;
      float dxg = g.px - fxp, dyg = g.py - fyp;
      float powg = -0.5f*(g.A*dxg*dxg + g.C*dyg*dyg) - g.B*dxg*dyg;
      float alphag = fminf(0.99f, g.op * __expf(powg));
      bool maybe = in && (powg <= 0.0f) && (alphag >= (1.0f/255.0f));
      if (!__syncthreads_or(maybe ? 1 : 0)) continue;

      float T = 1.0f;
      if (small) {
        for (int i = 0; i < S; ++i) {
          float4 qa = recA[i], qb = recB[i];
          float dx = qa.x - fxp, dy = qa.y - fyp;
          float power = -0.5f*(qa.z*dx*dx + qb.x*dy*dy) - qa.w*dx*dy;
          float alpha = fminf(0.99f, qb.y * __expf(power));
          bool keep = (power <= 0.0f) && (alpha >= (1.0f/255.0f));
          T -= keep ? alpha*T : 0.0f;
        }
      } else {
        for (int sb = 0; sb < S; sb += 512) {
          int cc = min(512, S - sb);
          for (int j = t; j < cc; j += 256) {
            int ci = (int)(skey[sb+j] & 1023u);
            PC r = proj_cull((b<<10)+ci, means, opac, scales, rots, vm, pm);
            recA[j] = make_float4(r.px, r.py, r.A, r.B);
            recB[j] = make_float4(r.C, r.op, 0.f, 0.f);
          }
          __syncthreads();
          for (int i = 0; i < cc; ++i) {
            float4 qa = recA[i], qb = recB[i];
            float dx = qa.x - fxp, dy = qa.y - fyp;
            float power = -0.5f*(qa.z*dx*dx + qb.x*dy*dy) - qa.w*dx*dy;
            float alpha = fminf(0.99f, qb.y * __expf(power));
            bool keep = (power <= 0.0f) && (alpha >= (1.0f/255.0f));
            T -= keep ? alpha*T : 0.0f;
          }
          __syncthreads();
        }
      }
      float wg = maybe ? alphag * T : 0.0f;
      if (maybe) {
        float t0v = target[((b*3+0)*HI + yi)*WI + xi];
        float t1v = target[((b*3+1)*HI + yi)*WI + xi];
        float t2v = target[((b*3+2)*HI + yi)*WI + xi];
        ec0 += wg*t0v; ec1 += wg*t1v; ec2 += wg*t2v; ew += wg;
      }
    }
    #pragma unroll
    for (int o = 32; o; o >>= 1) {
      ec0 += __shfl_xor(ec0, o); ec1 += __shfl_xor(ec1, o);
      ec2 += __shfl_xor(ec2, o); ew  += __shfl_xor(ew , o);
    }
    if (ln == 0) redbuf[wv] = make_float4(ec0, ec1, ec2, ew);
    __syncthreads();
    if (t == 0) {
      float4 r0 = redbuf[0], r1 = redbuf[1], r2 = redbuf[2], r3 = redbuf[3];
      out[OFF_ESTC + (b*PG + gi)*3 + 0] = r0.x+r1.x+r2.x+r3.x;
      out[OFF_ESTC + (b*PG + gi)*3 + 1] = r0.y+r1.y+r2.y+r3.y;
      out[OFF_ESTC + (b*PG + gi)*3 + 2] = r0.z+r1.z+r2.z+r3.z;
      out[OFF_ESTW + b*PG + gi]         = r0.w+r1.w+r2.w+r3.w;
    }
    return;
  }

  // ================= tile block: color / alpha (16x16 px, thread=pixel) =====
  const int tb = blk - NE;
  const int b = tb >> 6, tile = tb & 63;
  const int tx0 = (tile & 7) * 16, ty0 = (tile >> 3) * 16;
  const int xi = tx0 + (t & 15), yi = ty0 + (t >> 4);
  const float fxp = (float)xi, fyp = (float)yi;
  const float rx0 = (float)tx0, ry0 = (float)ty0;

  int cnt = 0;
  for (int k = 0; k < 4; ++k) {
    int ci = wv*256 + k*64 + ln;
    PC r = proj_cull((b<<10)+ci, means, opac, scales, rots, vm, pm);
    unsigned long long k64 = (((unsigned long long)r.key) << 10) | (unsigned)ci;
    bool ok = (r.px + r.ex >= rx0) && (r.px - r.ex <= rx0 + 15.0f)
           && (r.py + r.ey >= ry0) && (r.py - r.ey <= ry0 + 15.0f);
    unsigned long long m = __ballot(ok);
    if (ok) skey[wv*256 + cnt + __popcll(m & ((1ull<<ln)-1ull))] = k64;
    cnt += __popcll(m);
  }
  if (ln == 0) wcount[wv] = cnt;
  __syncthreads();
  int c0_=wcount[0], c1_=wcount[1], c2_=wcount[2], c3_=wcount[3];
  int total = c0_+c1_+c2_+c3_;
  int off = (wv>0?c0_:0)+(wv>1?c1_:0)+(wv>2?c2_:0);
  for (int i = ln; i < cnt; i += 64) {
    unsigned long long v = skey[wv*256 + i];
    skey[off + i] = v;
  }
  __syncthreads();
  block_sort(skey, total, t, wv, ln);

  float T = 1.0f, a0 = 0.f, a1 = 0.f, a2 = 0.f;
  for (int c = 0; c < total; c += 512) {
    int cc = min(512, total - c);
    for (int j = t; j < cc; j += 256) {
      int ci = (int)(skey[c+j] & 1023u);
      int e = (b<<10) + ci;
      PC r = proj_cull(e, means, opac, scales, rots, vm, pm);
      float col[3]; sh_color(e, sh, means, campos, col);
      recA[j] = make_float4(r.px, r.py, r.A, r.B);
      recB[j] = make_float4(r.C, r.op, 0.f, 0.f);
      colC[j] = make_float4(col[0], col[1], col[2], 0.f);
    }
    __syncthreads();
    for (int i = 0; i < cc; ++i) {
      float4 qa = recA[i], qb = recB[i], qc = colC[i];
      float dx = qa.x - fxp, dy = qa.y - fyp;
      float power = -0.5f*(qa.z*dx*dx + qb.x*dy*dy) - qa.w*dx*dy;
      float alpha = fminf(0.99f, qb.y * __expf(power));
      bool keep = (power <= 0.0f) && (alpha >= (1.0f/255.0f));
      float w_ = keep ? alpha * T : 0.0f;
      a0 += w_*qc.x; a1 += w_*qc.y; a2 += w_*qc.z;
      T -= w_;
    }
    __syncthreads();
  }

  out[((b*3+0)*HI + yi)*WI + xi] = a0 + T * bg[b*3+0];
  out[((b*3+1)*HI + yi)*WI + xi] = a1 + T * bg[b*3+1];
  out[((b*3+2)*HI + yi)*WI + xi] = a2 + T * bg[b*3+2];
  out[OFF_ALPHA + (b*HI + yi)*WI + xi] = 1.0f - T;
}

extern "C" void kernel_launch(void* const* d_in, const int* in_sizes, int n_in,
                              void* d_out, int out_size, void* d_ws, size_t ws_size,
                              hipStream_t stream) {
  const float* means  = (const float*)d_in[0];
  const float* sh     = (const float*)d_in[1];
  const float* opac   = (const float*)d_in[2];
  const float* scales = (const float*)d_in[3];
  const float* rots   = (const float*)d_in[4];
  const float* target = (const float*)d_in[5];
  const float* bg     = (const float*)d_in[6];
  const float* vm     = (const float*)d_in[7];
  const float* pm     = (const float*)d_in[8];
  const float* campos = (const float*)d_in[9];
  float* out = (float*)d_out;

  // est/radii blocks [0, NE) + tile blocks [NE, NE + BB*64)
  fused_kernel<<<NE + BB*64, 256, 0, stream>>>(
      means, sh, opac, scales, rots, vm, pm, campos, target, bg, out);
}